// Round 1
// baseline (419.946 us; speedup 1.0000x reference)
//
#include <hip/hip_runtime.h>

typedef __attribute__((ext_vector_type(8))) short short8;
typedef __attribute__((ext_vector_type(4))) float f32x4;

#define NROW 8192
#define D_SZ 512

// workspace byte offsets
#define HB_OFF    0u         // bf16 [8192][512]  = 8388608 B
#define POS_OFF   8388608u   // f32 [8192]
#define MPART_OFF 8421376u   // f32 [4][8192]
#define SPART_OFF 8552448u   // f32 [4][8192]
#define SLAB_OFF  8683520u   // f32 [256][256]
#define PSUM_OFF  8945664u   // f32 [256]
#define FSUM_OFF  8946688u   // f32 [1]

__device__ __forceinline__ unsigned short f32_to_bf16(float f) {
  unsigned int u = __float_as_uint(f);
  u = (u + 0x7FFFu + ((u >> 16) & 1u)) >> 16;
  return (unsigned short)u;
}

// zero S_label + psum + fsum (contiguous from SLAB_OFF): 65536+256+1 floats
__global__ void zero_kernel(float* __restrict__ z) {
  int i = blockIdx.x * 256 + threadIdx.x;
  if (i < 65793) z[i] = 0.f;
}

__global__ void convert_kernel(const float* __restrict__ h1, const float* __restrict__ h2,
                               unsigned short* __restrict__ hb) {
  int tid = blockIdx.x * 256 + threadIdx.x;  // float4 id, 1048576 total
  float4 v = (tid < 524288) ? reinterpret_cast<const float4*>(h1)[tid]
                            : reinterpret_cast<const float4*>(h2)[tid - 524288];
  ushort4 o;
  o.x = f32_to_bf16(v.x); o.y = f32_to_bf16(v.y);
  o.z = f32_to_bf16(v.z); o.w = f32_to_bf16(v.w);
  reinterpret_cast<ushort4*>(hb)[tid] = o;
}

// ---------------- feature NT-Xent: flash-style LSE over sim = hb hb^T * 2 --------------
__global__ __launch_bounds__(256, 2) void feature_kernel(
    const short* __restrict__ hb, float* __restrict__ pos,
    float* __restrict__ mpart, float* __restrict__ spart) {
  __shared__ short lds_s[32 * 512];  // 32 cols x 512 k (bf16), xor-swizzled
  const int tid = threadIdx.x;
  const int w = tid >> 6;
  const int lane = tid & 63;
  const int lo16 = lane & 15;
  const int grp = lane >> 4;
  const int cz = blockIdx.x;         // 0..3 column chunk (XCD-friendly: x fastest)
  const int bt = blockIdx.y;         // 0..63 row tile
  const int Rw = bt * 128 + w * 32;  // this wave's row base

  // A fragments in registers: 2 row-frags x full K
  short8 A[2][16];
#pragma unroll
  for (int rt = 0; rt < 2; ++rt) {
    const short* ab = hb + (Rw + rt * 16 + lo16) * D_SZ + grp * 8;
#pragma unroll
    for (int kk = 0; kk < 16; ++kk)
      A[rt][kk] = *reinterpret_cast<const short8*>(ab + kk * 32);
  }

  float m_run[2][4], s_run[2][4];
#pragma unroll
  for (int rt = 0; rt < 2; ++rt)
#pragma unroll
    for (int j = 0; j < 4; ++j) { m_run[rt][j] = -INFINITY; s_run[rt][j] = 0.f; }

  const int c0 = cz * 2048;
  const int swz = (lo16 & 7) << 3;  // element-index xor for 16B-slot spread

#pragma unroll 1
  for (int g = 0; g < 64; ++g) {
    const int cg = c0 + g * 32;
    __syncthreads();
    // stage 32 cols x 512 k of bf16 (32 KB), swizzled
#pragma unroll
    for (int i = 0; i < 8; ++i) {
      int ch = i * 256 + tid;
      int col = ch >> 6, k8 = ch & 63;
      short8 v = *reinterpret_cast<const short8*>(hb + (cg + col) * D_SZ + k8 * 8);
      int dst = col * D_SZ + ((k8 * 8) ^ ((col & 7) << 3));
      *reinterpret_cast<short8*>(&lds_s[dst]) = v;
    }
    __syncthreads();

    f32x4 acc00 = {0,0,0,0}, acc01 = {0,0,0,0}, acc10 = {0,0,0,0}, acc11 = {0,0,0,0};
#pragma unroll
    for (int kk = 0; kk < 16; ++kk) {
      const int k = kk * 32 + grp * 8;
      short8 B0 = *reinterpret_cast<const short8*>(&lds_s[(lo16 * D_SZ + k) ^ swz]);
      short8 B1 = *reinterpret_cast<const short8*>(&lds_s[((16 + lo16) * D_SZ + k) ^ swz]);
      acc00 = __builtin_amdgcn_mfma_f32_16x16x32_bf16(A[0][kk], B0, acc00, 0, 0, 0);
      acc01 = __builtin_amdgcn_mfma_f32_16x16x32_bf16(A[0][kk], B1, acc01, 0, 0, 0);
      acc10 = __builtin_amdgcn_mfma_f32_16x16x32_bf16(A[1][kk], B0, acc10, 0, 0, 0);
      acc11 = __builtin_amdgcn_mfma_f32_16x16x32_bf16(A[1][kk], B1, acc11, 0, 0, 0);
    }

    const int colA = cg + lo16;       // col of acc*0 for this lane
    const int colB = cg + 16 + lo16;  // col of acc*1
#pragma unroll
    for (int rt = 0; rt < 2; ++rt) {
      f32x4 a0 = rt ? acc10 : acc00;
      f32x4 a1 = rt ? acc11 : acc01;
#pragma unroll
      for (int j = 0; j < 4; ++j) {
        const int r = Rw + rt * 16 + grp * 4 + j;   // C/D: col=lane&15, row=(lane>>4)*4+j
        const int partner = (r + 4096) & 8191;
        float v0 = a0[j] * 2.0f;  // / TEMP_F
        float v1 = a1[j] * 2.0f;
        if (colA == r) v0 = -INFINITY;
        if (colB == r) v1 = -INFINITY;
        if (colA == partner) pos[r] = v0;
        if (colB == partner) pos[r] = v1;
        float tm = fmaxf(v0, v1);
#pragma unroll
        for (int off = 1; off < 16; off <<= 1) tm = fmaxf(tm, __shfl_xor(tm, off));
        const float mn = fmaxf(m_run[rt][j], tm);
        float e = __expf(v0 - mn) + __expf(v1 - mn);
#pragma unroll
        for (int off = 1; off < 16; off <<= 1) e += __shfl_xor(e, off);
        s_run[rt][j] = s_run[rt][j] * __expf(m_run[rt][j] - mn) + e;
        m_run[rt][j] = mn;
      }
    }
  }

  if (lo16 == 0) {
#pragma unroll
    for (int rt = 0; rt < 2; ++rt)
#pragma unroll
      for (int j = 0; j < 4; ++j) {
        const int r = Rw + rt * 16 + grp * 4 + j;
        mpart[cz * NROW + r] = m_run[rt][j];
        spart[cz * NROW + r] = s_run[rt][j];
      }
  }
}

__global__ void combine_feature_kernel(const float* __restrict__ mpart,
                                       const float* __restrict__ spart,
                                       const float* __restrict__ pos,
                                       const float* __restrict__ conf,
                                       float* __restrict__ fsum) {
  __shared__ float red[256];
  int r = blockIdx.x * 256 + threadIdx.x;
  float m0 = mpart[r], m1 = mpart[NROW + r], m2 = mpart[2 * NROW + r], m3 = mpart[3 * NROW + r];
  float M = fmaxf(fmaxf(m0, m1), fmaxf(m2, m3));
  float S = spart[r] * __expf(m0 - M) + spart[NROW + r] * __expf(m1 - M) +
            spart[2 * NROW + r] * __expf(m2 - M) + spart[3 * NROW + r] * __expf(m3 - M);
  float lse = logf(S) + M;
  float loss = (lse - pos[r]) * conf[r & 4095];
  red[threadIdx.x] = loss;
  __syncthreads();
  for (int s = 128; s > 0; s >>= 1) {
    if (threadIdx.x < s) red[threadIdx.x] += red[threadIdx.x + s];
    __syncthreads();
  }
  if (threadIdx.x == 0) atomicAdd(fsum, red[0]);
}

// ---------------- label path ----------------
__global__ void colsum_kernel(const float* __restrict__ q1, const float* __restrict__ q2,
                              float* __restrict__ psum) {
  __shared__ float sd[256];
  int t = threadIdx.x, bx = blockIdx.x;
  const float* q = (bx < 64) ? q1 : q2;
  int rb = (bx & 63) * 64;
  int c = t & 127, rs = t >> 7;
  float acc = 0.f;
  for (int i = 0; i < 32; ++i) acc += q[(rb + rs + 2 * i) * 128 + c];
  sd[t] = acc;
  __syncthreads();
  if (t < 128) atomicAdd(&psum[(bx >> 6) * 128 + c], sd[t] + sd[t + 128]);
}

// S = X^T X, X = [q1 | q2] (4096 x 256), split-K over blockIdx.y
__global__ __launch_bounds__(256) void label_gemm_kernel(const float* __restrict__ q1,
                                                         const float* __restrict__ q2,
                                                         float* __restrict__ S) {
  __shared__ float As[64][32];
  __shared__ float Bs[64][32];
  const int t = threadIdx.x;
  const int bx = blockIdx.x & 7, by = blockIdx.x >> 3;
  const int kz = blockIdx.y;
  const int tx = t & 15, ty = t >> 4;
  float a00 = 0, a01 = 0, a10 = 0, a11 = 0;
  for (int ch = 0; ch < 8; ++ch) {
    const int kbase = kz * 512 + ch * 64;
    __syncthreads();
#pragma unroll
    for (int i = 0; i < 8; ++i) {
      int e = i * 256 + t;
      int kr = e >> 5, j = e & 31;
      int ga = by * 32 + j;
      int gb = bx * 32 + j;
      As[kr][j] = (ga < 128) ? q1[(kbase + kr) * 128 + ga] : q2[(kbase + kr) * 128 + ga - 128];
      Bs[kr][j] = (gb < 128) ? q1[(kbase + kr) * 128 + gb] : q2[(kbase + kr) * 128 + gb - 128];
    }
    __syncthreads();
#pragma unroll 16
    for (int k = 0; k < 64; ++k) {
      float A0 = As[k][ty * 2], A1 = As[k][ty * 2 + 1];
      float B0 = Bs[k][tx * 2], B1 = Bs[k][tx * 2 + 1];
      a00 += A0 * B0; a01 += A0 * B1; a10 += A1 * B0; a11 += A1 * B1;
    }
  }
  int r0 = by * 32 + ty * 2, c0 = bx * 32 + tx * 2;
  atomicAdd(&S[r0 * 256 + c0], a00);
  atomicAdd(&S[r0 * 256 + c0 + 1], a01);
  atomicAdd(&S[(r0 + 1) * 256 + c0], a10);
  atomicAdd(&S[(r0 + 1) * 256 + c0 + 1], a11);
}

__global__ void label_final_kernel(const float* __restrict__ S, const float* __restrict__ psum,
                                   const float* __restrict__ fsum, float* __restrict__ out) {
  __shared__ float nrm[256];
  __shared__ float red[256], redl[256];
  __shared__ float entropy_sh;
  const int t = threadIdx.x;
  nrm[t] = sqrtf(fmaxf(S[t * 256 + t], 0.f));
  float v = psum[t];
  red[t] = v;
  redl[t] = v * logf(fmaxf(v, 1e-30f));
  __syncthreads();
  for (int s = 64; s > 0; s >>= 1) {
    if ((t & 127) < s) { red[t] += red[t + s]; redl[t] += redl[t + s]; }
    __syncthreads();
  }
  if (t == 0) {
    float tot1 = red[0], tot2 = red[128];
    float ne1 = logf(128.f) + (redl[0] / tot1 - logf(tot1));
    float ne2 = logf(128.f) + (redl[128] / tot2 - logf(tot2));
    entropy_sh = ne1 + ne2;
  }
  __syncthreads();

  const float nr = nrm[t];
  const float* Srow = S + t * 256;
  float m = -INFINITY;
  for (int c = 0; c < 256; ++c) {
    if (c == t) continue;
    float sv = Srow[c] / fmaxf(nr * nrm[c], 1e-8f);
    m = fmaxf(m, sv);
  }
  float ssum = 0.f, posv = 0.f;
  const int partner = (t + 128) & 255;
  for (int c = 0; c < 256; ++c) {
    float sv = Srow[c] / fmaxf(nr * nrm[c], 1e-8f);
    if (c == partner) posv = sv;
    if (c != t) ssum += __expf(sv - m);
  }
  float loss_r = (logf(ssum) + m) - posv;
  __syncthreads();
  red[t] = loss_r;
  __syncthreads();
  for (int s = 128; s > 0; s >>= 1) {
    if (t < s) red[t] += red[t + s];
    __syncthreads();
  }
  if (t == 0) {
    float label_loss = red[0] / 256.f + entropy_sh;
    float feat_loss = fsum[0] / 8192.f;
    out[0] = 0.5f * feat_loss + 0.5f * label_loss;
  }
}

extern "C" void kernel_launch(void* const* d_in, const int* in_sizes, int n_in,
                              void* d_out, int out_size, void* d_ws, size_t ws_size,
                              hipStream_t stream) {
  const float* h1 = (const float*)d_in[0];
  const float* h2 = (const float*)d_in[1];
  const float* q1 = (const float*)d_in[2];
  const float* q2 = (const float*)d_in[3];
  const float* conf = (const float*)d_in[4];
  float* out = (float*)d_out;
  char* ws = (char*)d_ws;

  unsigned short* hb = (unsigned short*)(ws + HB_OFF);
  float* pos   = (float*)(ws + POS_OFF);
  float* mpart = (float*)(ws + MPART_OFF);
  float* spart = (float*)(ws + SPART_OFF);
  float* Slab  = (float*)(ws + SLAB_OFF);
  float* psum  = (float*)(ws + PSUM_OFF);
  float* fsum  = (float*)(ws + FSUM_OFF);

  zero_kernel<<<258, 256, 0, stream>>>(Slab);  // zeroes Slab+psum+fsum (contiguous)
  convert_kernel<<<4096, 256, 0, stream>>>(h1, h2, hb);
  colsum_kernel<<<128, 256, 0, stream>>>(q1, q2, psum);
  label_gemm_kernel<<<dim3(64, 8), 256, 0, stream>>>(q1, q2, Slab);
  feature_kernel<<<dim3(4, 64), 256, 0, stream>>>((const short*)hb, pos, mpart, spart);
  combine_feature_kernel<<<32, 256, 0, stream>>>(mpart, spart, pos, conf, fsum);
  label_final_kernel<<<1, 256, 0, stream>>>(Slab, psum, fsum, out);
}

// Round 2
// 272.903 us; speedup vs baseline: 1.5388x; 1.5388x over previous
//
#include <hip/hip_runtime.h>

typedef __attribute__((ext_vector_type(8))) short short8;
typedef __attribute__((ext_vector_type(4))) float f32x4;

#define NROW 8192
#define D_SZ 512

// workspace byte offsets.
// Region [0, 8388608) holds hb (bf16 H) during the feature phase; after
// combine_feature it is DEAD and the label path reuses it:
#define HB_OFF     0u         // bf16 [8192][512] = 8388608 B   (feature phase)
#define SPARTL_OFF 0u         // f32 [8][256][256] = 2097152 B  (label phase, aliases hb)
#define SGRAM_OFF  2097152u   // f32 [256][256] = 262144 B      (label phase)
#define PSUMP_OFF  2359296u   // f32 [8][128] = 4096 B          (label phase)
#define FPART_OFF  2363392u   // f32 [32] (written pre-label_gemm? no: see order note)
#define POS_OFF    8388608u   // f32 [8192]
#define MPART_OFF  8421376u   // f32 [8][8192] = 262144 B
#define SPARTF_OFF 8683520u   // f32 [8][8192] = 262144 B
// NOTE order: convert, feature, combine_feature(writes FPART@2363392 — outside
// Spart's [0,2097152) and SGRAM's [2097152,2359296)? NO — 2363392 > 2359296, OK,
// and label_gemm/label_prep never write FPART) then label kernels. Max offset
// used = 8945664 <= round-0 footprint.

__device__ __forceinline__ unsigned short f32_to_bf16(float f) {
  unsigned int u = __float_as_uint(f);
  u = (u + 0x7FFFu + ((u >> 16) & 1u)) >> 16;
  return (unsigned short)u;
}

__global__ void convert_kernel(const float* __restrict__ h1, const float* __restrict__ h2,
                               unsigned short* __restrict__ hb) {
  int tid = blockIdx.x * 256 + threadIdx.x;  // float4 id, 1048576 total
  float4 v = (tid < 524288) ? reinterpret_cast<const float4*>(h1)[tid]
                            : reinterpret_cast<const float4*>(h2)[tid - 524288];
  ushort4 o;
  o.x = f32_to_bf16(v.x); o.y = f32_to_bf16(v.y);
  o.z = f32_to_bf16(v.z); o.w = f32_to_bf16(v.w);
  reinterpret_cast<ushort4*>(hb)[tid] = o;
}

// ---------------- feature NT-Xent: flash-style LSE over sim = hb hb^T * 2 ----------------
// Swapped-operand MFMA: acc = mfma(col_frag, row_frag) => D^T layout:
//   lane&15  -> row index within row-frag
//   (lane>>4)*4+j -> col index within col-frag
// so each lane holds 8 cols of ONE row per row-frag: row-reduce = in-lane + 2 shfl.
__global__ __launch_bounds__(256, 2) void feature_kernel(
    const short* __restrict__ hb, float* __restrict__ pos,
    float* __restrict__ mpart, float* __restrict__ spart) {
  __shared__ short lds_s[32 * 512];  // 32 cols x 512 k (bf16), xor-swizzled
  const int tid = threadIdx.x;
  const int w = tid >> 6;
  const int lane = tid & 63;
  const int lo16 = lane & 15;
  const int grp = lane >> 4;
  const int cz = blockIdx.x;         // 0..7 column chunk (x fastest -> chunk per XCD)
  const int bt = blockIdx.y;         // 0..63 row tile
  const int Rw = bt * 128 + w * 32;  // this wave's row base

  // A fragments in registers: 2 row-frags x full K (128 VGPRs), pinned.
  short8 A[2][16];
#pragma unroll
  for (int rt = 0; rt < 2; ++rt) {
    const short* ab = hb + (Rw + rt * 16 + lo16) * D_SZ + grp * 8;
#pragma unroll
    for (int kk = 0; kk < 16; ++kk)
      A[rt][kk] = *reinterpret_cast<const short8*>(ab + kk * 32);
  }
#pragma unroll
  for (int rt = 0; rt < 2; ++rt)
#pragma unroll
    for (int kk = 0; kk < 16; ++kk)
      asm volatile("" : "+v"(A[rt][kk]));  // forbid rematerialization of A loads

  float m0 = -INFINITY, m1 = -INFINITY, s0 = 0.f, s1 = 0.f;
  const int r0 = Rw + lo16;
  const int r1 = Rw + 16 + lo16;
  const int p0 = (r0 + 4096) & 8191;
  const int p1 = (r1 + 4096) & 8191;
  const int swz = (lo16 & 7) << 3;   // element-index xor (16B-slot spread)

#pragma unroll 1
  for (int g = 0; g < 32; ++g) {
    const int cg = cz * 1024 + g * 32;
    __syncthreads();
    // stage 32 cols x 512 k of bf16 (32 KB), swizzled
#pragma unroll
    for (int i = 0; i < 8; ++i) {
      int ch = i * 256 + tid;
      int col = ch >> 6, k8 = ch & 63;
      short8 v = *reinterpret_cast<const short8*>(hb + (cg + col) * D_SZ + k8 * 8);
      int dst = col * D_SZ + ((k8 * 8) ^ ((col & 7) << 3));
      *reinterpret_cast<short8*>(&lds_s[dst]) = v;
    }
    __syncthreads();

    f32x4 acc00 = {0,0,0,0}, acc01 = {0,0,0,0}, acc10 = {0,0,0,0}, acc11 = {0,0,0,0};
    // accXY: X = col-frag (0: cols cg..cg+15, 1: cg+16..31), Y = row-frag
#pragma unroll
    for (int kk = 0; kk < 16; ++kk) {
      const int k = kk * 32 + grp * 8;
      short8 B0 = *reinterpret_cast<const short8*>(&lds_s[lo16 * D_SZ + (k ^ swz)]);
      short8 B1 = *reinterpret_cast<const short8*>(&lds_s[(16 + lo16) * D_SZ + (k ^ swz)]);
      acc00 = __builtin_amdgcn_mfma_f32_16x16x32_bf16(B0, A[0][kk], acc00, 0, 0, 0);
      acc01 = __builtin_amdgcn_mfma_f32_16x16x32_bf16(B0, A[1][kk], acc01, 0, 0, 0);
      acc10 = __builtin_amdgcn_mfma_f32_16x16x32_bf16(B1, A[0][kk], acc10, 0, 0, 0);
      acc11 = __builtin_amdgcn_mfma_f32_16x16x32_bf16(B1, A[1][kk], acc11, 0, 0, 0);
    }

    const int cbase = cg + grp * 4;
    // ---- row-frag 0 (row r0) ----
    {
      float v[8];
#pragma unroll
      for (int j = 0; j < 4; ++j) { v[j] = acc00[j] * 2.f; v[4 + j] = acc10[j] * 2.f; }
#pragma unroll
      for (int j = 0; j < 4; ++j) {
        int c0 = cbase + j, c1 = cbase + 16 + j;
        if (c0 == p0) pos[r0] = v[j];
        if (c1 == p0) pos[r0] = v[4 + j];
        if (c0 == r0) v[j] = -INFINITY;
        if (c1 == r0) v[4 + j] = -INFINITY;
      }
      float tm = v[0];
#pragma unroll
      for (int i = 1; i < 8; ++i) tm = fmaxf(tm, v[i]);
      tm = fmaxf(tm, __shfl_xor(tm, 16));
      tm = fmaxf(tm, __shfl_xor(tm, 32));
      float mn = fmaxf(m0, tm);
      float e = 0.f;
#pragma unroll
      for (int i = 0; i < 8; ++i) e += __expf(v[i] - mn);
      e += __shfl_xor(e, 16);
      e += __shfl_xor(e, 32);
      s0 = s0 * __expf(m0 - mn) + e;
      m0 = mn;
    }
    // ---- row-frag 1 (row r1) ----
    {
      float v[8];
#pragma unroll
      for (int j = 0; j < 4; ++j) { v[j] = acc01[j] * 2.f; v[4 + j] = acc11[j] * 2.f; }
#pragma unroll
      for (int j = 0; j < 4; ++j) {
        int c0 = cbase + j, c1 = cbase + 16 + j;
        if (c0 == p1) pos[r1] = v[j];
        if (c1 == p1) pos[r1] = v[4 + j];
        if (c0 == r1) v[j] = -INFINITY;
        if (c1 == r1) v[4 + j] = -INFINITY;
      }
      float tm = v[0];
#pragma unroll
      for (int i = 1; i < 8; ++i) tm = fmaxf(tm, v[i]);
      tm = fmaxf(tm, __shfl_xor(tm, 16));
      tm = fmaxf(tm, __shfl_xor(tm, 32));
      float mn = fmaxf(m1, tm);
      float e = 0.f;
#pragma unroll
      for (int i = 0; i < 8; ++i) e += __expf(v[i] - mn);
      e += __shfl_xor(e, 16);
      e += __shfl_xor(e, 32);
      s1 = s1 * __expf(m1 - mn) + e;
      m1 = mn;
    }
  }

  if (grp == 0) {
    mpart[cz * NROW + r0] = m0; spart[cz * NROW + r0] = s0;
    mpart[cz * NROW + r1] = m1; spart[cz * NROW + r1] = s1;
  }
}

__global__ void combine_feature_kernel(const float* __restrict__ mpart,
                                       const float* __restrict__ spart,
                                       const float* __restrict__ pos,
                                       const float* __restrict__ conf,
                                       float* __restrict__ fpart) {
  __shared__ float red[256];
  int r = blockIdx.x * 256 + threadIdx.x;
  float M = -INFINITY;
#pragma unroll
  for (int k = 0; k < 8; ++k) M = fmaxf(M, mpart[k * NROW + r]);
  float S = 0.f;
#pragma unroll
  for (int k = 0; k < 8; ++k) S += spart[k * NROW + r] * __expf(mpart[k * NROW + r] - M);
  float lse = logf(S) + M;
  float loss = (lse - pos[r]) * conf[r & 4095];
  red[threadIdx.x] = loss;
  __syncthreads();
  for (int s = 128; s > 0; s >>= 1) {
    if (threadIdx.x < s) red[threadIdx.x] += red[threadIdx.x + s];
    __syncthreads();
  }
  if (threadIdx.x == 0) fpart[blockIdx.x] = red[0];
}

// ---------------- label path: S = X^T X, X = [q1 | q2] (4096 x 256), f32 ----------------
// grid 256: kz = b>>5 (8-way split-K), bi = (b&31)>>3 (4 row-tiles of 64),
// bj = b&7 (8 col-tiles of 32). 4x2 micro-tile per thread, partials -> Spart (no atomics).
__global__ __launch_bounds__(256) void label_gemm_kernel(const float* __restrict__ q1,
                                                         const float* __restrict__ q2,
                                                         float* __restrict__ Spart) {
  __shared__ float As[32 * 64];
  __shared__ float Bs[32 * 32];
  const int t = threadIdx.x;
  const int kz = blockIdx.x >> 5;
  const int bi = (blockIdx.x & 31) >> 3;
  const int bj = blockIdx.x & 7;
  const int tx = t & 15, ty = t >> 4;
  float a[4][2];
#pragma unroll
  for (int dr = 0; dr < 4; ++dr)
#pragma unroll
    for (int dc = 0; dc < 2; ++dc) a[dr][dc] = 0.f;

  for (int ch = 0; ch < 16; ++ch) {
    const int kbase = kz * 512 + ch * 32;
    __syncthreads();
#pragma unroll
    for (int i = 0; i < 8; ++i) {
      int e = i * 256 + t;
      int kr = e >> 6, j = e & 63;
      int ca = bi * 64 + j;
      As[kr * 64 + j] = (ca < 128) ? q1[(kbase + kr) * 128 + ca]
                                   : q2[(kbase + kr) * 128 + ca - 128];
    }
#pragma unroll
    for (int i = 0; i < 4; ++i) {
      int e = i * 256 + t;
      int kr = e >> 5, j = e & 31;
      int cb = bj * 32 + j;
      Bs[kr * 32 + j] = (cb < 128) ? q1[(kbase + kr) * 128 + cb]
                                   : q2[(kbase + kr) * 128 + cb - 128];
    }
    __syncthreads();
#pragma unroll 8
    for (int k = 0; k < 32; ++k) {
      float4 Av = *reinterpret_cast<const float4*>(&As[k * 64 + ty * 4]);
      float2 Bv = *reinterpret_cast<const float2*>(&Bs[k * 32 + tx * 2]);
      a[0][0] += Av.x * Bv.x; a[0][1] += Av.x * Bv.y;
      a[1][0] += Av.y * Bv.x; a[1][1] += Av.y * Bv.y;
      a[2][0] += Av.z * Bv.x; a[2][1] += Av.z * Bv.y;
      a[3][0] += Av.w * Bv.x; a[3][1] += Av.w * Bv.y;
    }
  }
  float* outp = Spart + kz * 65536;
#pragma unroll
  for (int dr = 0; dr < 4; ++dr) {
    int r = bi * 64 + ty * 4 + dr;
    int c = bj * 32 + tx * 2;
    outp[r * 256 + c] = a[dr][0];
    outp[r * 256 + c + 1] = a[dr][1];
  }
}

// b<256: combine Spart -> S. b>=256: column sums of q1/q2 -> psum_part (no atomics).
__global__ void label_prep_kernel(const float* __restrict__ q1, const float* __restrict__ q2,
                                  const float* __restrict__ Spart, float* __restrict__ S,
                                  float* __restrict__ psum_part) {
  const int b = blockIdx.x, t = threadIdx.x;
  if (b < 256) {
    int e = b * 256 + t;
    float acc = 0.f;
#pragma unroll
    for (int kz = 0; kz < 8; ++kz) acc += Spart[kz * 65536 + e];
    S[e] = acc;
  } else {
    __shared__ float sd[256];
    int idx = b - 256;  // 0..7: q = idx>>2, row-chunk = idx&3
    const float* q = (idx < 4) ? q1 : q2;
    int col = t & 127, half = t >> 7;
    int rbase = (idx & 3) * 1024 + half * 512;
    float acc = 0.f;
    for (int i = 0; i < 512; ++i) acc += q[(rbase + i) * 128 + col];
    sd[t] = acc;
    __syncthreads();
    if (t < 128) psum_part[idx * 128 + col] = sd[t] + sd[t + 128];
  }
}

__global__ __launch_bounds__(256) void label_final_kernel(
    const float* __restrict__ S, const float* __restrict__ psum_part,
    const float* __restrict__ fpart, float* __restrict__ out) {
  __shared__ float nrm[256], red[256], redl[256];
  __shared__ float entropy_sh, feat_sh;
  const int t = threadIdx.x;
  nrm[t] = sqrtf(fmaxf(S[t * 257], 0.f));
  const float* pp = psum_part + (t >> 7) * 512 + (t & 127);
  float v = pp[0] + pp[128] + pp[256] + pp[384];
  red[t] = v;
  redl[t] = v * logf(fmaxf(v, 1e-30f));
  __syncthreads();
  for (int s = 64; s > 0; s >>= 1) {
    if ((t & 127) < s) { red[t] += red[t + s]; redl[t] += redl[t + s]; }
    __syncthreads();
  }
  if (t == 0) {
    float tot1 = red[0], tot2 = red[128];
    float ne1 = logf(128.f) + (redl[0] / tot1 - logf(tot1));
    float ne2 = logf(128.f) + (redl[128] / tot2 - logf(tot2));
    entropy_sh = ne1 + ne2;
  }
  __syncthreads();
  red[t] = (t < 32) ? fpart[t] : 0.f;
  __syncthreads();
  for (int s = 128; s > 0; s >>= 1) {
    if (t < s) red[t] += red[t + s];
    __syncthreads();
  }
  if (t == 0) feat_sh = red[0];
  __syncthreads();

  const float nr = nrm[t];
  const float* Srow = S + t * 256;
  const int partner = (t + 128) & 255;
  float m = -INFINITY;
  for (int c = 0; c < 256; ++c) {
    if (c == t) continue;
    float sv = Srow[c] / fmaxf(nr * nrm[c], 1e-8f);
    m = fmaxf(m, sv);
  }
  float ssum = 0.f, posv = 0.f;
  for (int c = 0; c < 256; ++c) {
    float sv = Srow[c] / fmaxf(nr * nrm[c], 1e-8f);
    if (c == partner) posv = sv;
    if (c != t) ssum += __expf(sv - m);
  }
  float loss_r = (logf(ssum) + m) - posv;
  __syncthreads();
  red[t] = loss_r;
  __syncthreads();
  for (int s = 128; s > 0; s >>= 1) {
    if (t < s) red[t] += red[t + s];
    __syncthreads();
  }
  if (t == 0)
    out[0] = 0.5f * (feat_sh / 8192.f) + 0.5f * (red[0] / 256.f + entropy_sh);
}

extern "C" void kernel_launch(void* const* d_in, const int* in_sizes, int n_in,
                              void* d_out, int out_size, void* d_ws, size_t ws_size,
                              hipStream_t stream) {
  const float* h1 = (const float*)d_in[0];
  const float* h2 = (const float*)d_in[1];
  const float* q1 = (const float*)d_in[2];
  const float* q2 = (const float*)d_in[3];
  const float* conf = (const float*)d_in[4];
  float* out = (float*)d_out;
  char* ws = (char*)d_ws;

  unsigned short* hb = (unsigned short*)(ws + HB_OFF);
  float* pos    = (float*)(ws + POS_OFF);
  float* mpart  = (float*)(ws + MPART_OFF);
  float* spartf = (float*)(ws + SPARTF_OFF);
  float* SpartL = (float*)(ws + SPARTL_OFF);
  float* Sgram  = (float*)(ws + SGRAM_OFF);
  float* psump  = (float*)(ws + PSUMP_OFF);
  float* fpart  = (float*)(ws + FPART_OFF);

  convert_kernel<<<4096, 256, 0, stream>>>(h1, h2, hb);
  feature_kernel<<<dim3(8, 64), 256, 0, stream>>>((const short*)hb, pos, mpart, spartf);
  combine_feature_kernel<<<32, 256, 0, stream>>>(mpart, spartf, pos, conf, fpart);
  // hb region is dead from here on; label path reuses it.
  label_gemm_kernel<<<256, 256, 0, stream>>>(q1, q2, SpartL);
  label_prep_kernel<<<264, 256, 0, stream>>>(q1, q2, SpartL, Sgram, psump);
  label_final_kernel<<<1, 256, 0, stream>>>(Sgram, psump, fpart, out);
}

// Round 3
// 269.099 us; speedup vs baseline: 1.5606x; 1.0141x over previous
//
#include <hip/hip_runtime.h>

typedef __attribute__((ext_vector_type(8))) short short8;
typedef __attribute__((ext_vector_type(4))) float f32x4;

#define NROW 8192
#define D_SZ 512

// workspace byte offsets.
// Region [0, 8388608) holds hb (bf16 H) during the feature phase; after
// combine_feature it is DEAD and the label path reuses it:
#define HB_OFF     0u         // bf16 [8192][512] = 8388608 B   (feature phase)
#define SPARTL_OFF 0u         // f32 [8][256][256] = 2097152 B  (label phase, aliases hb)
#define SGRAM_OFF  2097152u   // f32 [256][256] = 262144 B      (label phase)
#define PSUMP_OFF  2359296u   // f32 [8][128] = 4096 B          (label phase)
#define FPART_OFF  2363392u   // f32 [32] (combine_feature output; label kernels never touch)
#define POS_OFF    8388608u   // f32 [8192]
#define MPART_OFF  8421376u   // f32 [8][8192] = 262144 B
#define SPARTF_OFF 8683520u   // f32 [8][8192] = 262144 B

// async global->LDS, 16B per lane; LDS dest must be linear (uniform base + lane*16)
#define GLOAD_LDS(gp, lp)                                     \
  __builtin_amdgcn_global_load_lds(                           \
      (const __attribute__((address_space(1))) void*)(gp),    \
      (__attribute__((address_space(3))) void*)(lp), 16, 0, 0)

__device__ __forceinline__ unsigned short f32_to_bf16(float f) {
  unsigned int u = __float_as_uint(f);
  u = (u + 0x7FFFu + ((u >> 16) & 1u)) >> 16;
  return (unsigned short)u;
}

__global__ void convert_kernel(const float* __restrict__ h1, const float* __restrict__ h2,
                               unsigned short* __restrict__ hb) {
  int tid = blockIdx.x * 256 + threadIdx.x;  // float4 id, 1048576 total
  float4 v = (tid < 524288) ? reinterpret_cast<const float4*>(h1)[tid]
                            : reinterpret_cast<const float4*>(h2)[tid - 524288];
  ushort4 o;
  o.x = f32_to_bf16(v.x); o.y = f32_to_bf16(v.y);
  o.z = f32_to_bf16(v.z); o.w = f32_to_bf16(v.w);
  reinterpret_cast<ushort4*>(hb)[tid] = o;
}

// ---------------- feature NT-Xent: flash-style LSE over sim = hb hb^T * 2 ----------------
// Swapped-operand MFMA: acc = mfma(col_frag, row_frag) => each lane holds 8 cols of ONE
// row per row-frag. Per-group epilogue keeps per-lane-group partial (m,s); merged across
// the 4 lane-groups once at kernel end (butterfly shfl).
// Staging: double-buffered global_load_lds with pre-swizzled global source:
//   LDS[col][c] = hb[col][c ^ (col&7)]  (16B chunks c=0..63 per column)
// Read side retrieves chunk q of col as LDS[col][q ^ (col&7)] -> bank-spread b128 reads.
__global__ __launch_bounds__(256, 2) void feature_kernel(
    const short* __restrict__ hb, float* __restrict__ pos,
    float* __restrict__ mpart, float* __restrict__ spart) {
  __shared__ short lds_s[2][16384];  // 2 x 32KB: 32 cols x 512 k bf16, swizzled
  const int tid = threadIdx.x;
  const int w = tid >> 6;
  const int lane = tid & 63;
  const int lo16 = lane & 15;
  const int grp = lane >> 4;
  const int cz = blockIdx.x;         // 0..7 column chunk (x fastest -> chunk per XCD)
  const int bt = blockIdx.y;         // 0..63 row tile
  const int Rw = bt * 128 + w * 32;  // this wave's row base

  // A fragments in registers: 2 row-frags x full K (128 VGPRs), pinned IN the loop.
  short8 A[2][16];
#pragma unroll
  for (int rt = 0; rt < 2; ++rt) {
    const short* ab = hb + (Rw + rt * 16 + lo16) * D_SZ + grp * 8;
#pragma unroll
    for (int kk = 0; kk < 16; ++kk)
      A[rt][kk] = *reinterpret_cast<const short8*>(ab + kk * 32);
  }

  // staging pointers: wave w stages cols {i*4+w}, chunk index = lane, source chunk
  // pre-swizzled: lane ^ ((i*4+w)&7) = lane ^ (w + 4*(i&1))
  const short* p_even = hb + (cz * 1024 + w) * D_SZ + (lane ^ w) * 8;
  const short* p_odd  = hb + (cz * 1024 + w) * D_SZ + (lane ^ (w + 4)) * 8;
  short* ldbase = &lds_s[0][tid * 8];

  // group g source advance: g*32 cols * 512 = g*16384 elements (same stride as buffers)
#define STAGE(g, b) do {                                   \
    const short* pe_ = p_even + (g) * 16384;               \
    const short* po_ = p_odd + (g) * 16384;                \
    short* ld_ = ldbase + (b) * 16384;                     \
    GLOAD_LDS(pe_, ld_);                                   \
    GLOAD_LDS(po_ + 2048, ld_ + 2048);                     \
    GLOAD_LDS(pe_ + 4096, ld_ + 4096);                     \
    GLOAD_LDS(po_ + 6144, ld_ + 6144);                     \
    GLOAD_LDS(pe_ + 8192, ld_ + 8192);                     \
    GLOAD_LDS(po_ + 10240, ld_ + 10240);                   \
    GLOAD_LDS(pe_ + 12288, ld_ + 12288);                   \
    GLOAD_LDS(po_ + 14336, ld_ + 14336);                   \
  } while (0)

  float m0 = -INFINITY, m1 = -INFINITY, s0 = 0.f, s1 = 0.f;
  const int r0 = Rw + lo16;
  const int r1 = Rw + 16 + lo16;
  const int p0 = (r0 + 4096) & 8191;
  const int p1 = (r1 + 4096) & 8191;
  const int swz = (lo16 & 7) << 3;   // element-index xor (16B-chunk spread)

  STAGE(0, 0);
  __syncthreads();  // compiler drains vmcnt before s_barrier -> buf0 ready

#pragma unroll 1
  for (int g = 0; g < 32; ++g) {
    const int cur = g & 1;
    if (g < 31) STAGE(g + 1, cur ^ 1);  // async prefetch, lands before end-of-iter barrier

    // pin A every iteration: forbids remat/spill of the resident fragments
#pragma unroll
    for (int rt = 0; rt < 2; ++rt)
#pragma unroll
      for (int kk = 0; kk < 16; ++kk)
        asm volatile("" : "+v"(A[rt][kk]));

    const short* bufp = &lds_s[cur][0];
    f32x4 acc00 = {0,0,0,0}, acc01 = {0,0,0,0}, acc10 = {0,0,0,0}, acc11 = {0,0,0,0};
    // accXY: X = col-frag (0: cols +0..15, 1: +16..31), Y = row-frag
#pragma unroll
    for (int kk = 0; kk < 16; ++kk) {
      const int k = kk * 32 + grp * 8;
      short8 B0 = *reinterpret_cast<const short8*>(&bufp[lo16 * D_SZ + (k ^ swz)]);
      short8 B1 = *reinterpret_cast<const short8*>(&bufp[(16 + lo16) * D_SZ + (k ^ swz)]);
      acc00 = __builtin_amdgcn_mfma_f32_16x16x32_bf16(B0, A[0][kk], acc00, 0, 0, 0);
      acc01 = __builtin_amdgcn_mfma_f32_16x16x32_bf16(B0, A[1][kk], acc01, 0, 0, 0);
      acc10 = __builtin_amdgcn_mfma_f32_16x16x32_bf16(B1, A[0][kk], acc10, 0, 0, 0);
      acc11 = __builtin_amdgcn_mfma_f32_16x16x32_bf16(B1, A[1][kk], acc11, 0, 0, 0);
    }

    const int cbase = cz * 1024 + g * 32 + grp * 4;
    // ---- row-frag 0 (row r0): per-lane-group partial, no shfl ----
    {
      float v[8];
#pragma unroll
      for (int j = 0; j < 4; ++j) { v[j] = acc00[j] * 2.f; v[4 + j] = acc10[j] * 2.f; }
#pragma unroll
      for (int j = 0; j < 4; ++j) {
        int c0 = cbase + j, c1 = cbase + 16 + j;
        if (c0 == p0) pos[r0] = v[j];
        if (c1 == p0) pos[r0] = v[4 + j];
        if (c0 == r0) v[j] = -INFINITY;
        if (c1 == r0) v[4 + j] = -INFINITY;
      }
      float tm = fmaxf(fmaxf(fmaxf(v[0], v[1]), fmaxf(v[2], v[3])),
                       fmaxf(fmaxf(v[4], v[5]), fmaxf(v[6], v[7])));
      float mn = fmaxf(m0, tm);
      float e = 0.f;
#pragma unroll
      for (int i = 0; i < 8; ++i) e += __expf(v[i] - mn);
      s0 = s0 * __expf(m0 - mn) + e;
      m0 = mn;
    }
    // ---- row-frag 1 (row r1) ----
    {
      float v[8];
#pragma unroll
      for (int j = 0; j < 4; ++j) { v[j] = acc01[j] * 2.f; v[4 + j] = acc11[j] * 2.f; }
#pragma unroll
      for (int j = 0; j < 4; ++j) {
        int c0 = cbase + j, c1 = cbase + 16 + j;
        if (c0 == p1) pos[r1] = v[j];
        if (c1 == p1) pos[r1] = v[4 + j];
        if (c0 == r1) v[j] = -INFINITY;
        if (c1 == r1) v[4 + j] = -INFINITY;
      }
      float tm = fmaxf(fmaxf(fmaxf(v[0], v[1]), fmaxf(v[2], v[3])),
                       fmaxf(fmaxf(v[4], v[5]), fmaxf(v[6], v[7])));
      float mn = fmaxf(m1, tm);
      float e = 0.f;
#pragma unroll
      for (int i = 0; i < 8; ++i) e += __expf(v[i] - mn);
      s1 = s1 * __expf(m1 - mn) + e;
      m1 = mn;
    }

    __syncthreads();  // one barrier/group: drains prefetch vmcnt + guards buffer swap
  }

  // merge per-lane-group partials across the 4 groups (butterfly over lane bits 4,5)
#pragma unroll
  for (int off = 16; off <= 32; off <<= 1) {
    float mo = __shfl_xor(m0, off), so = __shfl_xor(s0, off);
    float mn = fmaxf(m0, mo);
    s0 = s0 * __expf(m0 - mn) + so * __expf(mo - mn);
    m0 = mn;
    mo = __shfl_xor(m1, off); so = __shfl_xor(s1, off);
    mn = fmaxf(m1, mo);
    s1 = s1 * __expf(m1 - mn) + so * __expf(mo - mn);
    m1 = mn;
  }

  if (grp == 0) {
    mpart[cz * NROW + r0] = m0; spart[cz * NROW + r0] = s0;
    mpart[cz * NROW + r1] = m1; spart[cz * NROW + r1] = s1;
  }
#undef STAGE
}

__global__ void combine_feature_kernel(const float* __restrict__ mpart,
                                       const float* __restrict__ spart,
                                       const float* __restrict__ pos,
                                       const float* __restrict__ conf,
                                       float* __restrict__ fpart) {
  __shared__ float red[256];
  int r = blockIdx.x * 256 + threadIdx.x;
  float M = -INFINITY;
#pragma unroll
  for (int k = 0; k < 8; ++k) M = fmaxf(M, mpart[k * NROW + r]);
  float S = 0.f;
#pragma unroll
  for (int k = 0; k < 8; ++k) S += spart[k * NROW + r] * __expf(mpart[k * NROW + r] - M);
  float lse = logf(S) + M;
  float loss = (lse - pos[r]) * conf[r & 4095];
  red[threadIdx.x] = loss;
  __syncthreads();
  for (int s = 128; s > 0; s >>= 1) {
    if (threadIdx.x < s) red[threadIdx.x] += red[threadIdx.x + s];
    __syncthreads();
  }
  if (threadIdx.x == 0) fpart[blockIdx.x] = red[0];
}

// ---------------- label path: S = X^T X, X = [q1 | q2] (4096 x 256), f32 ----------------
__global__ __launch_bounds__(256) void label_gemm_kernel(const float* __restrict__ q1,
                                                         const float* __restrict__ q2,
                                                         float* __restrict__ Spart) {
  __shared__ float As[32 * 64];
  __shared__ float Bs[32 * 32];
  const int t = threadIdx.x;
  const int kz = blockIdx.x >> 5;
  const int bi = (blockIdx.x & 31) >> 3;
  const int bj = blockIdx.x & 7;
  const int tx = t & 15, ty = t >> 4;
  float a[4][2];
#pragma unroll
  for (int dr = 0; dr < 4; ++dr)
#pragma unroll
    for (int dc = 0; dc < 2; ++dc) a[dr][dc] = 0.f;

  for (int ch = 0; ch < 16; ++ch) {
    const int kbase = kz * 512 + ch * 32;
    __syncthreads();
#pragma unroll
    for (int i = 0; i < 8; ++i) {
      int e = i * 256 + t;
      int kr = e >> 6, j = e & 63;
      int ca = bi * 64 + j;
      As[kr * 64 + j] = (ca < 128) ? q1[(kbase + kr) * 128 + ca]
                                   : q2[(kbase + kr) * 128 + ca - 128];
    }
#pragma unroll
    for (int i = 0; i < 4; ++i) {
      int e = i * 256 + t;
      int kr = e >> 5, j = e & 31;
      int cb = bj * 32 + j;
      Bs[kr * 32 + j] = (cb < 128) ? q1[(kbase + kr) * 128 + cb]
                                   : q2[(kbase + kr) * 128 + cb - 128];
    }
    __syncthreads();
#pragma unroll 8
    for (int k = 0; k < 32; ++k) {
      float4 Av = *reinterpret_cast<const float4*>(&As[k * 64 + ty * 4]);
      float2 Bv = *reinterpret_cast<const float2*>(&Bs[k * 32 + tx * 2]);
      a[0][0] += Av.x * Bv.x; a[0][1] += Av.x * Bv.y;
      a[1][0] += Av.y * Bv.x; a[1][1] += Av.y * Bv.y;
      a[2][0] += Av.z * Bv.x; a[2][1] += Av.z * Bv.y;
      a[3][0] += Av.w * Bv.x; a[3][1] += Av.w * Bv.y;
    }
  }
  float* outp = Spart + kz * 65536;
#pragma unroll
  for (int dr = 0; dr < 4; ++dr) {
    int r = bi * 64 + ty * 4 + dr;
    int c = bj * 32 + tx * 2;
    outp[r * 256 + c] = a[dr][0];
    outp[r * 256 + c + 1] = a[dr][1];
  }
}

// b<256: combine Spart -> S. b>=256: column sums of q1/q2 -> psum_part (no atomics).
__global__ void label_prep_kernel(const float* __restrict__ q1, const float* __restrict__ q2,
                                  const float* __restrict__ Spart, float* __restrict__ S,
                                  float* __restrict__ psum_part) {
  const int b = blockIdx.x, t = threadIdx.x;
  if (b < 256) {
    int e = b * 256 + t;
    float acc = 0.f;
#pragma unroll
    for (int kz = 0; kz < 8; ++kz) acc += Spart[kz * 65536 + e];
    S[e] = acc;
  } else {
    __shared__ float sd[256];
    int idx = b - 256;  // 0..7: q = idx>>2, row-chunk = idx&3
    const float* q = (idx < 4) ? q1 : q2;
    int col = t & 127, half = t >> 7;
    int rbase = (idx & 3) * 1024 + half * 512;
    float acc = 0.f;
    for (int i = 0; i < 512; ++i) acc += q[(rbase + i) * 128 + col];
    sd[t] = acc;
    __syncthreads();
    if (t < 128) psum_part[idx * 128 + col] = sd[t] + sd[t + 128];
  }
}

__global__ __launch_bounds__(256) void label_final_kernel(
    const float* __restrict__ S, const float* __restrict__ psum_part,
    const float* __restrict__ fpart, float* __restrict__ out) {
  __shared__ float nrm[256], red[256], redl[256];
  __shared__ float entropy_sh, feat_sh;
  const int t = threadIdx.x;
  nrm[t] = sqrtf(fmaxf(S[t * 257], 0.f));
  const float* pp = psum_part + (t >> 7) * 512 + (t & 127);
  float v = pp[0] + pp[128] + pp[256] + pp[384];
  red[t] = v;
  redl[t] = v * logf(fmaxf(v, 1e-30f));
  __syncthreads();
  for (int s = 64; s > 0; s >>= 1) {
    if ((t & 127) < s) { red[t] += red[t + s]; redl[t] += redl[t + s]; }
    __syncthreads();
  }
  if (t == 0) {
    float tot1 = red[0], tot2 = red[128];
    float ne1 = logf(128.f) + (redl[0] / tot1 - logf(tot1));
    float ne2 = logf(128.f) + (redl[128] / tot2 - logf(tot2));
    entropy_sh = ne1 + ne2;
  }
  __syncthreads();
  red[t] = (t < 32) ? fpart[t] : 0.f;
  __syncthreads();
  for (int s = 128; s > 0; s >>= 1) {
    if (t < s) red[t] += red[t + s];
    __syncthreads();
  }
  if (t == 0) feat_sh = red[0];
  __syncthreads();

  const float nr = nrm[t];
  const float* Srow = S + t * 256;
  const int partner = (t + 128) & 255;
  float m = -INFINITY;
  for (int c = 0; c < 256; ++c) {
    if (c == t) continue;
    float sv = Srow[c] / fmaxf(nr * nrm[c], 1e-8f);
    m = fmaxf(m, sv);
  }
  float ssum = 0.f, posv = 0.f;
  for (int c = 0; c < 256; ++c) {
    float sv = Srow[c] / fmaxf(nr * nrm[c], 1e-8f);
    if (c == partner) posv = sv;
    if (c != t) ssum += __expf(sv - m);
  }
  float loss_r = (logf(ssum) + m) - posv;
  __syncthreads();
  red[t] = loss_r;
  __syncthreads();
  for (int s = 128; s > 0; s >>= 1) {
    if (t < s) red[t] += red[t + s];
    __syncthreads();
  }
  if (t == 0)
    out[0] = 0.5f * (feat_sh / 8192.f) + 0.5f * (red[0] / 256.f + entropy_sh);
}

extern "C" void kernel_launch(void* const* d_in, const int* in_sizes, int n_in,
                              void* d_out, int out_size, void* d_ws, size_t ws_size,
                              hipStream_t stream) {
  const float* h1 = (const float*)d_in[0];
  const float* h2 = (const float*)d_in[1];
  const float* q1 = (const float*)d_in[2];
  const float* q2 = (const float*)d_in[3];
  const float* conf = (const float*)d_in[4];
  float* out = (float*)d_out;
  char* ws = (char*)d_ws;

  unsigned short* hb = (unsigned short*)(ws + HB_OFF);
  float* pos    = (float*)(ws + POS_OFF);
  float* mpart  = (float*)(ws + MPART_OFF);
  float* spartf = (float*)(ws + SPARTF_OFF);
  float* SpartL = (float*)(ws + SPARTL_OFF);
  float* Sgram  = (float*)(ws + SGRAM_OFF);
  float* psump  = (float*)(ws + PSUMP_OFF);
  float* fpart  = (float*)(ws + FPART_OFF);

  convert_kernel<<<4096, 256, 0, stream>>>(h1, h2, hb);
  feature_kernel<<<dim3(8, 64), 256, 0, stream>>>((const short*)hb, pos, mpart, spartf);
  combine_feature_kernel<<<32, 256, 0, stream>>>(mpart, spartf, pos, conf, fpart);
  // hb region is dead from here on; label path reuses it.
  label_gemm_kernel<<<256, 256, 0, stream>>>(q1, q2, SpartL);
  label_prep_kernel<<<264, 256, 0, stream>>>(q1, q2, SpartL, Sgram, psump);
  label_final_kernel<<<1, 256, 0, stream>>>(Sgram, psump, fpart, out);
}

// Round 5
// 220.628 us; speedup vs baseline: 1.9034x; 1.2197x over previous
//
#include <hip/hip_runtime.h>

typedef __attribute__((ext_vector_type(8))) short short8;
typedef __attribute__((ext_vector_type(4))) float f32x4;

#define NROW 8192
#define D_SZ 512

// workspace byte offsets.
// Region [0, 8388608) holds hb (bf16 H) during the feature phase; after
// combine_feature it is DEAD and the label path reuses it:
#define HB_OFF     0u         // bf16 [8192][512] = 8388608 B   (feature phase)
#define SPARTL_OFF 0u         // f32 [16][256][256] = 4194304 B (label phase, aliases hb)
#define SGRAM_OFF  4194304u   // f32 [256][256] = 262144 B
#define PSUMP_OFF  4456448u   // f32 [32][128] = 16384 B
#define FPART_OFF  4472832u   // f32 [32]
#define POS_OFF    8388608u   // f32 [8192]
#define MPART_OFF  8421376u   // f32 [8][8192] = 262144 B
#define SPARTF_OFF 8683520u   // f32 [8][8192] = 262144 B

// async global->LDS, 16B per lane; LDS dest must be linear (uniform base + lane*16)
#define GLOAD_LDS(gp, lp)                                     \
  __builtin_amdgcn_global_load_lds(                           \
      (const __attribute__((address_space(1))) void*)(gp),    \
      (__attribute__((address_space(3))) void*)(lp), 16, 0, 0)

__device__ __forceinline__ unsigned short f32_to_bf16(float f) {
  unsigned int u = __float_as_uint(f);
  u = (u + 0x7FFFu + ((u >> 16) & 1u)) >> 16;
  return (unsigned short)u;
}

__global__ void convert_kernel(const float* __restrict__ h1, const float* __restrict__ h2,
                               unsigned short* __restrict__ hb) {
  int tid = blockIdx.x * 256 + threadIdx.x;  // float4 id, 1048576 total
  float4 v = (tid < 524288) ? reinterpret_cast<const float4*>(h1)[tid]
                            : reinterpret_cast<const float4*>(h2)[tid - 524288];
  ushort4 o;
  o.x = f32_to_bf16(v.x); o.y = f32_to_bf16(v.y);
  o.z = f32_to_bf16(v.z); o.w = f32_to_bf16(v.w);
  reinterpret_cast<ushort4*>(hb)[tid] = o;
}

// ---------------- feature NT-Xent: flash-style LSE over sim = hb hb^T * 2 ----------------
// m201-shape: 256x256 block tile, 8 waves (2 row-halves x 4 col-quarters),
// wave tile 128x64, BK=64 double-buffered A+B LDS (128 KB), 1 block/CU.
// Swapped-operand MFMA: acc[cf][rf] = mfma(ColFrag, RowFrag) -> lane holds
// row = R0+wr*128+rf*16+(lane&15), cols = C0+wc*64+cf*16+(lane>>4)*4+j.
// LDS involution swizzle: LDS[row][ch] = glob[row][ch ^ (row&7)] (16B chunks),
// staged via linear-dest gload_lds from inverse-swizzled global addresses.
__global__ __launch_bounds__(512, 2) void feature_kernel(
    const short* __restrict__ hb, float* __restrict__ pos,
    float* __restrict__ mpart, float* __restrict__ spart) {
  __shared__ short lds_s[2][2][16384];  // [buf][A=0/B=1][256 rows x 64 k] bf16 swizzled
  const int tid = threadIdx.x;
  const int w = tid >> 6;
  const int lane = tid & 63;
  const int lo16 = lane & 15;
  const int grp = lane >> 4;
  const int lo7 = lo16 & 7;
  const int wr = w >> 2;            // 0..1 row-half
  const int wc = w & 3;             // 0..3 col-quarter
  const int cz = blockIdx.x;        // 0..7 col-chunk
  const int bt = blockIdx.y;        // 0..31 row-tile
  const int R0 = bt * 256;
  const int CZ0 = cz * 1024;

  // staging: thread stages chunk (tid&7) of rows {i*64 + (tid>>3)}, i=0..3, per tile.
  // source chunk pre-swizzled by row&7 = (tid>>3)&7 (constant per thread).
  const int srow = tid >> 3;
  const int csrc = (tid & 7) ^ (srow & 7);
  const short* baseA = hb + (size_t)(R0 + srow) * D_SZ + csrc * 8;
  const short* baseB = hb + (size_t)(CZ0 + srow) * D_SZ + csrc * 8;

#define STAGE_STEP(ct_, bk_, buf_) do {                        \
    const short* sa_ = baseA + (bk_) * 64;                     \
    const short* sb_ = baseB + (ct_) * 131072 + (bk_) * 64;    \
    short* da_ = &lds_s[buf_][0][tid * 8];                     \
    short* db_ = &lds_s[buf_][1][tid * 8];                     \
    GLOAD_LDS(sa_, da_);                  GLOAD_LDS(sb_, db_);                  \
    GLOAD_LDS(sa_ + 32768, da_ + 4096);   GLOAD_LDS(sb_ + 32768, db_ + 4096);   \
    GLOAD_LDS(sa_ + 65536, da_ + 8192);   GLOAD_LDS(sb_ + 65536, db_ + 8192);   \
    GLOAD_LDS(sa_ + 98304, da_ + 12288);  GLOAD_LDS(sb_ + 98304, db_ + 12288);  \
  } while (0)

  float mrun[8], srun[8];
#pragma unroll
  for (int rf = 0; rf < 8; ++rf) { mrun[rf] = -INFINITY; srun[rf] = 0.f; }

  f32x4 acc[4][8];
#pragma unroll
  for (int cf = 0; cf < 4; ++cf)
#pragma unroll
    for (int rf = 0; rf < 8; ++rf) acc[cf][rf] = (f32x4){0, 0, 0, 0};

  const int rowbaseA = (wr * 128 + lo16) * 64;  // elem offset of lane's A row
  const int colbaseB = (wc * 64 + lo16) * 64;   // elem offset of lane's B col-row

  STAGE_STEP(0, 0, 0);
  __syncthreads();

#pragma unroll 1
  for (int step = 0; step < 32; ++step) {
    const int ct = step >> 3, bk = step & 7, buf = step & 1;
    if (step < 31) {
      const int s2 = step + 1;
      STAGE_STEP(s2 >> 3, s2 & 7, buf ^ 1);
    }
    const short* pA = &lds_s[buf][0][0];
    const short* pB = &lds_s[buf][1][0];

#pragma unroll
    for (int ksub = 0; ksub < 2; ++ksub) {
      const int chsw = ((ksub * 4 + grp) ^ lo7) * 8;
      short8 cf_[4], rf_[8];
#pragma unroll
      for (int cf = 0; cf < 4; ++cf)
        cf_[cf] = *reinterpret_cast<const short8*>(&pB[colbaseB + cf * 1024 + chsw]);
#pragma unroll
      for (int rf = 0; rf < 8; ++rf)
        rf_[rf] = *reinterpret_cast<const short8*>(&pA[rowbaseA + rf * 1024 + chsw]);
#pragma unroll
      for (int cf = 0; cf < 4; ++cf)
#pragma unroll
        for (int rf = 0; rf < 8; ++rf)
          acc[cf][rf] = __builtin_amdgcn_mfma_f32_16x16x32_bf16(cf_[cf], rf_[rf],
                                                                acc[cf][rf], 0, 0, 0);
    }

    if (bk == 7) {
      // epilogue for col-tile ct: cols [C0, C0+256)
      const int C0 = CZ0 + ct * 256;
      const bool hd = (C0 == R0);
      const bool hp = (C0 == ((R0 + 4096) & 8191));
#pragma unroll
      for (int rf = 0; rf < 8; ++rf) {
        const int row = R0 + wr * 128 + rf * 16 + lo16;
        float v[16];
#pragma unroll
        for (int cf = 0; cf < 4; ++cf)
#pragma unroll
          for (int j = 0; j < 4; ++j) v[cf * 4 + j] = acc[cf][rf][j] * 2.f;
        if (hd || hp) {
          const int prow = (row + 4096) & 8191;
#pragma unroll
          for (int cf = 0; cf < 4; ++cf)
#pragma unroll
            for (int j = 0; j < 4; ++j) {
              const int c = C0 + wc * 64 + cf * 16 + grp * 4 + j;
              if (hp && c == prow) pos[row] = v[cf * 4 + j];
              if (hd && c == row) v[cf * 4 + j] = -INFINITY;
            }
        }
        float tm = v[0];
#pragma unroll
        for (int i = 1; i < 16; ++i) tm = fmaxf(tm, v[i]);
        const float mn = fmaxf(mrun[rf], tm);
        float e = 0.f;
#pragma unroll
        for (int i = 0; i < 16; ++i) e += __expf(v[i] - mn);
        srun[rf] = srun[rf] * __expf(mrun[rf] - mn) + e;
        mrun[rf] = mn;
#pragma unroll
        for (int cf = 0; cf < 4; ++cf) acc[cf][rf] = (f32x4){0, 0, 0, 0};
      }
    }
    __syncthreads();
  }

  // merge the 4 grp-copies of each row (lanes 16/32 apart hold same row, diff cols)
#pragma unroll
  for (int rf = 0; rf < 8; ++rf) {
#pragma unroll
    for (int off = 16; off <= 32; off <<= 1) {
      float mo = __shfl_xor(mrun[rf], off), so = __shfl_xor(srun[rf], off);
      float mn = fmaxf(mrun[rf], mo);
      srun[rf] = srun[rf] * __expf(mrun[rf] - mn) + so * __expf(mo - mn);
      mrun[rf] = mn;
    }
  }

  // cross-wave (wc) merge via LDS, then write per-chunk partials
  float* marr = reinterpret_cast<float*>(&lds_s[0][0][0]);  // [2][4][8][16]
  float* sarr = marr + 1024;
  if (grp == 0) {
#pragma unroll
    for (int rf = 0; rf < 8; ++rf) {
      const int idx = ((wr * 4 + wc) * 8 + rf) * 16 + lo16;
      marr[idx] = mrun[rf];
      sarr[idx] = srun[rf];
    }
  }
  __syncthreads();
  if (tid < 256) {
    const int row = tid;
    const int wr2 = row >> 7, rf2 = (row >> 4) & 7, lo2 = row & 15;
    float M = -INFINITY, S = 0.f;
#pragma unroll
    for (int wc2 = 0; wc2 < 4; ++wc2) {
      const int idx = ((wr2 * 4 + wc2) * 8 + rf2) * 16 + lo2;
      const float m = marr[idx], s = sarr[idx];
      const float mn = fmaxf(M, m);
      S = S * __expf(M - mn) + s * __expf(m - mn);
      M = mn;
    }
    mpart[cz * NROW + R0 + row] = M;
    spart[cz * NROW + R0 + row] = S;
  }
#undef STAGE_STEP
}

__global__ void combine_feature_kernel(const float* __restrict__ mpart,
                                       const float* __restrict__ spart,
                                       const float* __restrict__ pos,
                                       const float* __restrict__ conf,
                                       float* __restrict__ fpart) {
  __shared__ float red[256];
  int r = blockIdx.x * 256 + threadIdx.x;
  float M = -INFINITY;
#pragma unroll
  for (int k = 0; k < 8; ++k) M = fmaxf(M, mpart[k * NROW + r]);
  float S = 0.f;
#pragma unroll
  for (int k = 0; k < 8; ++k) S += spart[k * NROW + r] * __expf(mpart[k * NROW + r] - M);
  float lse = logf(S) + M;
  float loss = (lse - pos[r]) * conf[r & 4095];
  red[threadIdx.x] = loss;
  __syncthreads();
  for (int s = 128; s > 0; s >>= 1) {
    if (threadIdx.x < s) red[threadIdx.x] += red[threadIdx.x + s];
    __syncthreads();
  }
  if (threadIdx.x == 0) fpart[blockIdx.x] = red[0];
}

// ---------------- label path: S = X^T X, X = [q1 | q2] (4096 x 256), f32 ----------------
// grid 256: kz = b>>4 (16-way split-K), bi = (b>>2)&3, bj = b&3 (64x64 tiles).
// 4x4 micro-tile per thread; partials -> Spart (no atomics).
__global__ __launch_bounds__(256) void label_gemm_kernel(const float* __restrict__ q1,
                                                         const float* __restrict__ q2,
                                                         float* __restrict__ Spart) {
  __shared__ float As[32 * 64];
  __shared__ float Bs[32 * 64];
  const int t = threadIdx.x;
  const int kz = blockIdx.x >> 4;
  const int bi = (blockIdx.x >> 2) & 3;
  const int bj = blockIdx.x & 3;
  const int tx = t & 15, ty = t >> 4;
  float a[4][4];
#pragma unroll
  for (int dr = 0; dr < 4; ++dr)
#pragma unroll
    for (int dc = 0; dc < 4; ++dc) a[dr][dc] = 0.f;

  for (int ch = 0; ch < 8; ++ch) {
    const int kbase = kz * 256 + ch * 32;
    __syncthreads();
#pragma unroll
    for (int i = 0; i < 8; ++i) {
      int e = i * 256 + t;
      int kr = e >> 6, j = e & 63;
      int ca = bi * 64 + j;
      int cb = bj * 64 + j;
      As[kr * 64 + j] = (ca < 128) ? q1[(kbase + kr) * 128 + ca]
                                   : q2[(kbase + kr) * 128 + ca - 128];
      Bs[kr * 64 + j] = (cb < 128) ? q1[(kbase + kr) * 128 + cb]
                                   : q2[(kbase + kr) * 128 + cb - 128];
    }
    __syncthreads();
#pragma unroll 8
    for (int k = 0; k < 32; ++k) {
      float4 Av = *reinterpret_cast<const float4*>(&As[k * 64 + ty * 4]);
      float4 Bv = *reinterpret_cast<const float4*>(&Bs[k * 64 + tx * 4]);
      a[0][0] += Av.x * Bv.x; a[0][1] += Av.x * Bv.y; a[0][2] += Av.x * Bv.z; a[0][3] += Av.x * Bv.w;
      a[1][0] += Av.y * Bv.x; a[1][1] += Av.y * Bv.y; a[1][2] += Av.y * Bv.z; a[1][3] += Av.y * Bv.w;
      a[2][0] += Av.z * Bv.x; a[2][1] += Av.z * Bv.y; a[2][2] += Av.z * Bv.z; a[2][3] += Av.z * Bv.w;
      a[3][0] += Av.w * Bv.x; a[3][1] += Av.w * Bv.y; a[3][2] += Av.w * Bv.z; a[3][3] += Av.w * Bv.w;
    }
  }
  float* outp = Spart + (size_t)kz * 65536;
#pragma unroll
  for (int dr = 0; dr < 4; ++dr) {
    int r = bi * 64 + ty * 4 + dr;
    int c = bj * 64 + tx * 4;
    float4 o = {a[dr][0], a[dr][1], a[dr][2], a[dr][3]};
    *reinterpret_cast<float4*>(&outp[r * 256 + c]) = o;
  }
}

// b<256: combine Spart -> S. b>=256 (32 blocks): column sums of q1/q2 -> psum_part.
__global__ void label_prep_kernel(const float* __restrict__ q1, const float* __restrict__ q2,
                                  const float* __restrict__ Spart, float* __restrict__ S,
                                  float* __restrict__ psum_part) {
  const int b = blockIdx.x, t = threadIdx.x;
  if (b < 256) {
    int e = b * 256 + t;
    float acc = 0.f;
#pragma unroll
    for (int kz = 0; kz < 16; ++kz) acc += Spart[(size_t)kz * 65536 + e];
    S[e] = acc;
  } else {
    __shared__ float sd[256];
    int idx = b - 256;  // 0..31: q = idx>>4, row-block = idx&15
    const float* q = (idx < 16) ? q1 : q2;
    int col = t & 127, rh = t >> 7;
    int rbase = (idx & 15) * 256 + rh;
    float acc = 0.f;
    for (int i = 0; i < 128; ++i) acc += q[(rbase + 2 * i) * 128 + col];
    sd[t] = acc;
    __syncthreads();
    if (t < 128) psum_part[idx * 128 + col] = sd[t] + sd[t + 128];
  }
}

__global__ __launch_bounds__(256) void label_final_kernel(
    const float* __restrict__ S, const float* __restrict__ psum_part,
    const float* __restrict__ fpart, float* __restrict__ out) {
  __shared__ float nrm[256], red[256], redl[256];
  __shared__ float entropy_sh, feat_sh;
  const int t = threadIdx.x;
  nrm[t] = sqrtf(fmaxf(S[t * 257], 0.f));
  const float* pp = psum_part + (t >> 7) * 2048 + (t & 127);
  float v = 0.f;
#pragma unroll
  for (int i = 0; i < 16; ++i) v += pp[i * 128];
  red[t] = v;
  redl[t] = v * logf(fmaxf(v, 1e-30f));
  __syncthreads();
  for (int s = 64; s > 0; s >>= 1) {
    if ((t & 127) < s) { red[t] += red[t + s]; redl[t] += redl[t + s]; }
    __syncthreads();
  }
  if (t == 0) {
    float tot1 = red[0], tot2 = red[128];
    float ne1 = logf(128.f) + (redl[0] / tot1 - logf(tot1));
    float ne2 = logf(128.f) + (redl[128] / tot2 - logf(tot2));
    entropy_sh = ne1 + ne2;
  }
  __syncthreads();
  red[t] = (t < 32) ? fpart[t] : 0.f;
  __syncthreads();
  for (int s = 128; s > 0; s >>= 1) {
    if (t < s) red[t] += red[t + s];
    __syncthreads();
  }
  if (t == 0) feat_sh = red[0];
  __syncthreads();

  const float nr = nrm[t];
  const float* Srow = S + t * 256;
  const int partner = (t + 128) & 255;
  float m = -INFINITY;
  for (int c = 0; c < 256; ++c) {
    if (c == t) continue;
    float sv = Srow[c] / fmaxf(nr * nrm[c], 1e-8f);
    m = fmaxf(m, sv);
  }
  float ssum = 0.f, posv = 0.f;
  for (int c = 0; c < 256; ++c) {
    float sv = Srow[c] / fmaxf(nr * nrm[c], 1e-8f);
    if (c == partner) posv = sv;
    if (c != t) ssum += __expf(sv - m);
  }
  float loss_r = (logf(ssum) + m) - posv;
  __syncthreads();
  red[t] = loss_r;
  __syncthreads();
  for (int s = 128; s > 0; s >>= 1) {
    if (t < s) red[t] += red[t + s];
    __syncthreads();
  }
  if (t == 0)
    out[0] = 0.5f * (feat_sh / 8192.f) + 0.5f * (red[0] / 256.f + entropy_sh);
}

extern "C" void kernel_launch(void* const* d_in, const int* in_sizes, int n_in,
                              void* d_out, int out_size, void* d_ws, size_t ws_size,
                              hipStream_t stream) {
  const float* h1 = (const float*)d_in[0];
  const float* h2 = (const float*)d_in[1];
  const float* q1 = (const float*)d_in[2];
  const float* q2 = (const float*)d_in[3];
  const float* conf = (const float*)d_in[4];
  float* out = (float*)d_out;
  char* ws = (char*)d_ws;

  unsigned short* hb = (unsigned short*)(ws + HB_OFF);
  float* pos    = (float*)(ws + POS_OFF);
  float* mpart  = (float*)(ws + MPART_OFF);
  float* spartf = (float*)(ws + SPARTF_OFF);
  float* SpartL = (float*)(ws + SPARTL_OFF);
  float* Sgram  = (float*)(ws + SGRAM_OFF);
  float* psump  = (float*)(ws + PSUMP_OFF);
  float* fpart  = (float*)(ws + FPART_OFF);

  convert_kernel<<<4096, 256, 0, stream>>>(h1, h2, hb);
  feature_kernel<<<dim3(8, 32), 512, 0, stream>>>((const short*)hb, pos, mpart, spartf);
  combine_feature_kernel<<<32, 256, 0, stream>>>(mpart, spartf, pos, conf, fpart);
  // hb region is dead from here on; label path reuses it.
  label_gemm_kernel<<<256, 256, 0, stream>>>(q1, q2, SpartL);
  label_prep_kernel<<<288, 256, 0, stream>>>(q1, q2, SpartL, Sgram, psump);
  label_final_kernel<<<1, 256, 0, stream>>>(Sgram, psump, fpart, out);
}